// Round 2
// baseline (4527.519 us; speedup 1.0000x reference)
//
#include <hip/hip_runtime.h>
#include <math.h>

#define HH 4096
#define WW 4096
#define NB 64      // blocks (pipeline stages)
#define RPB 64     // rows per block == lanes per block (1 wave)
#define U 8        // column unroll / prefetch group

// halo slot layout in d_ws: for block b, slot jj (0..WW-1) holds the block's
// bottom-2-row activations *after* column jj-1 (jj=0 holds the initial x).
// Each entry: low 32 = float bits, high 32 = tag (jj+1). Poison 0xAAAAAAAA
// never equals a valid tag (1..4096), so unwritten slots always mismatch.
// All publishes/reads are device-scope RMW atomics so they execute at the
// cross-XCD coherence point (round-1's relaxed agent load/store showed
// ~60us visibility latency = L2-eviction-limited staleness).
// Size: NB * WW * 2 * 8B = 4 MiB.

struct Pref {
    float w8[U], b8[U];
    float wa1[U], wa2[U];        // w rows r0-1, r0-2 (lanes<2 only)
    unsigned long long h[U];     // halo entry for THIS lane's slot (lanes<2 only)
};

__global__ __launch_bounds__(64, 1) void neural_grid_scan(
    const float* __restrict__ x, const float* __restrict__ w,
    const float* __restrict__ bb, float* __restrict__ out,
    unsigned long long* __restrict__ halo)
{
    const int blk  = blockIdx.x;
    const int lane = threadIdx.x;
    const int row  = blk * RPB + lane;

    const float* wp  = w  + (size_t)row * WW;
    const float* bp  = bb + (size_t)row * WW;
    const float* wl1 = w + (size_t)(row - 1) * WW;  // valid only lane<2 && blk>0
    const float* wl2 = w + (size_t)(row - 2) * WW;

    float a = x[row];

    // publish initial state (column -1 == x) into slot 0, tag 1
    if (lane >= RPB - 2) {
        unsigned long long v = (1ULL << 32) | (unsigned long long)__float_as_uint(a);
        atomicExch(&halo[((size_t)blk * WW + 0) * 2 + (lane - (RPB - 2))], v);
    }

    // lane 0 polls slot *2+0 (row r0-2), lane 1 polls slot *2+1 (row r0-1)
    unsigned long long* hsrc = halo + ((size_t)(blk - 1) * WW) * 2;

    auto loadGroup = [&](int j, Pref& P) {
        *(float4*)&P.w8[0] = *(const float4*)(wp + j);
        *(float4*)&P.w8[4] = *(const float4*)(wp + j + 4);
        *(float4*)&P.b8[0] = *(const float4*)(bp + j);
        *(float4*)&P.b8[4] = *(const float4*)(bp + j + 4);
        if (lane < 2 && blk > 0) {
            *(float4*)&P.wa1[0] = *(const float4*)(wl1 + j);
            *(float4*)&P.wa1[4] = *(const float4*)(wl1 + j + 4);
            *(float4*)&P.wa2[0] = *(const float4*)(wl2 + j);
            *(float4*)&P.wa2[4] = *(const float4*)(wl2 + j + 4);
#pragma unroll
            for (int k = 0; k < U; ++k) {
                // coherent "load": RMW with identity, executes at coherence point
                P.h[k] = atomicOr(&hsrc[(size_t)(j + k) * 2 + lane], 0ULL);
            }
        }
    };

    Pref cur, nxt;
    loadGroup(0, cur);

    for (int j = 0; j < WW; j += U) {
        if (j + U < WW) loadGroup(j + U, nxt);
#pragma unroll
        for (int k = 0; k < U; ++k) {
            const int col = j + k;
            float wj = cur.w8[k];
            float bj = cur.b8[k];
            float am1 = __shfl_up(a, 1);
            float am2 = __shfl_up(a, 2);
            float wm1 = __shfl_up(wj, 1);
            float wm2 = __shfl_up(wj, 2);
            if (lane < 2) {
                if (blk > 0) {
                    const unsigned tagexp = (unsigned)(col + 1);
                    unsigned long long got = cur.h[k];
                    unsigned long long* myslot = &hsrc[(size_t)col * 2 + lane];
                    while ((unsigned)(got >> 32) != tagexp) {
                        got = atomicOr(myslot, 0ULL);   // both lanes poll in ONE op
                    }
                    unsigned long long v0 = __shfl(got, 0); // row r0-2 halo
                    unsigned long long v1 = __shfl(got, 1); // row r0-1 halo
                    float aup1 = __uint_as_float((unsigned)(v1 & 0xffffffffu));
                    float aup2 = __uint_as_float((unsigned)(v0 & 0xffffffffu));
                    if (lane == 0) { am1 = aup1; am2 = aup2; wm1 = cur.wa1[k]; wm2 = cur.wa2[k]; }
                    else           { am2 = aup1; wm2 = cur.wa1[k]; }
                } else {
                    if (lane == 0) { am1 = 0.f; am2 = 0.f; }
                    else           { am2 = 0.f; }
                }
            }
            float z = fmaf(am2, wm2, fmaf(am1, wm1, fmaf(a, wj, bj)));
            a = sinf(z);
            if (lane >= RPB - 2) {
                const int jj = col + 1;
                if (jj < WW) {
                    unsigned long long v = ((unsigned long long)(unsigned)(jj + 1) << 32)
                                         | (unsigned long long)__float_as_uint(a);
                    atomicExch(&halo[((size_t)blk * WW + jj) * 2 + (lane - (RPB - 2))], v);
                }
            }
        }
        cur = nxt;
    }

    out[row] = a;
}

extern "C" void kernel_launch(void* const* d_in, const int* in_sizes, int n_in,
                              void* d_out, int out_size, void* d_ws, size_t ws_size,
                              hipStream_t stream) {
    const float* x = (const float*)d_in[0];
    const float* w = (const float*)d_in[1];
    const float* b = (const float*)d_in[2];
    float* out = (float*)d_out;
    unsigned long long* halo = (unsigned long long*)d_ws;
    neural_grid_scan<<<dim3(NB), dim3(64), 0, stream>>>(x, w, b, out, halo);
}

// Round 3
// 1590.641 us; speedup vs baseline: 2.8463x; 2.8463x over previous
//
#include <hip/hip_runtime.h>
#include <math.h>

#define HH 4096
#define WW 4096
#define NB 64
#define U 8

// halo slots: halo[(blk*WW + col)*2 + s]; s=0 -> block's row 62 (consumer's r0-2),
// s=1 -> row 63 (r0-1). Value after column col-1 (col=0 holds initial x).
// Entry: low32 = float bits, high32 = tag (col+1). Poison 0xAAAAAAAA never
// matches tags 1..4096. 4 MiB total.

__device__ __forceinline__ float f4c(const float4& v, int k) {
    return (k == 0) ? v.x : ((k == 1) ? v.y : ((k == 2) ? v.z : v.w));
}

#define LOADW(J, W0, W1, W2, BV)                                             \
    do {                                                                     \
        W0[0] = *(const float4*)(wp  + (J));  W0[1] = *(const float4*)(wp  + (J) + 4); \
        W1[0] = *(const float4*)(wp1 + (J));  W1[1] = *(const float4*)(wp1 + (J) + 4); \
        W2[0] = *(const float4*)(wp2 + (J));  W2[1] = *(const float4*)(wp2 + (J) + 4); \
        BV[0] = *(const float4*)(bp  + (J));  BV[1] = *(const float4*)(bp  + (J) + 4); \
    } while (0)

#define LOADH(J, HG)                                                         \
    do {                                                                     \
        HG = (blk > 0 && lane < 16)                                          \
                 ? atomicOr(&hsrc[(size_t)(J) * 2 + lane], 0ULL) : 0ULL;     \
    } while (0)

#define COMPUTE8(JB, W0, W1, W2, BV, HG)                                     \
    _Pragma("unroll")                                                        \
    for (int k = 0; k < U; ++k) {                                            \
        const int col = (JB) + k;                                            \
        const unsigned tagexp = (unsigned)(col + 1);                         \
        unsigned long long hlo = __shfl(HG, 2 * k);                          \
        unsigned long long hhi = __shfl(HG, 2 * k + 1);                      \
        if (blk > 0) {                                                       \
            bool ok = ((unsigned)(hlo >> 32) == tagexp) &&                   \
                      ((unsigned)(hhi >> 32) == tagexp);                     \
            if (!ok) {  /* rare: fill transient */                           \
                unsigned long long t = 0;                                    \
                if (lane < 2) {                                              \
                    unsigned long long* p = &hsrc[(size_t)col * 2 + lane];   \
                    do { t = atomicOr(p, 0ULL); }                            \
                    while ((unsigned)(t >> 32) != tagexp);                   \
                }                                                            \
                hlo = __shfl(t, 0);                                          \
                hhi = __shfl(t, 1);                                          \
            }                                                                \
        }                                                                    \
        const float hloF = (blk > 0) ? __uint_as_float((unsigned)hlo) : 0.f; \
        const float hhiF = (blk > 0) ? __uint_as_float((unsigned)hhi) : 0.f; \
        float am1 = __shfl_up(a, 1);                                         \
        float am2 = __shfl_up(a, 2);                                         \
        am1 = (lane == 0) ? hhiF : am1;                                      \
        am2 = (lane == 0) ? hloF : ((lane == 1) ? hhiF : am2);               \
        const float wj  = f4c(W0[k >> 2], k & 3);                            \
        const float w1j = f4c(W1[k >> 2], k & 3);                            \
        const float w2j = f4c(W2[k >> 2], k & 3);                            \
        const float bj  = f4c(BV[k >> 2], k & 3);                            \
        const float z = fmaf(am2, w2j, fmaf(am1, w1j, fmaf(a, wj, bj)));     \
        a = sinf(z);                                                         \
        if (lane >= 62 && col + 1 < WW) {                                    \
            unsigned long long v =                                           \
                ((unsigned long long)(unsigned)(col + 2) << 32) |            \
                (unsigned long long)__float_as_uint(a);                      \
            atomicExch(&hme[(size_t)(col + 1) * 2 + (lane - 62)], v);        \
        }                                                                    \
    }

__global__ __launch_bounds__(64, 1) void neural_grid_scan(
    const float* __restrict__ x, const float* __restrict__ w,
    const float* __restrict__ bb, float* __restrict__ out,
    unsigned long long* __restrict__ halo)
{
    const int blk  = blockIdx.x;
    const int lane = threadIdx.x;
    const int row  = blk * 64 + lane;
    const int r1 = (row >= 1) ? row - 1 : 0;   // am1==0 there, w value unused
    const int r2 = (row >= 2) ? row - 2 : 0;

    const float* wp  = w  + (size_t)row * WW;
    const float* wp1 = w  + (size_t)r1  * WW;
    const float* wp2 = w  + (size_t)r2  * WW;
    const float* bp  = bb + (size_t)row * WW;

    unsigned long long* hme  = halo + (size_t)blk * WW * 2;
    unsigned long long* hsrc = halo + (size_t)(blk - 1) * WW * 2;

    float a = x[row];

    // publish initial state (column -1 == x) into slot 0, tag 1
    if (lane >= 62) {
        unsigned long long v = (1ULL << 32) | (unsigned long long)__float_as_uint(a);
        atomicExch(&hme[(size_t)(lane - 62)], v);
    }

    float4 Aw0[2], Aw1[2], Aw2[2], Ab[2];
    float4 Bw0[2], Bw1[2], Bw2[2], Bb[2];
    unsigned long long Ah = 0, Bh = 0;

    LOADW(0, Aw0, Aw1, Aw2, Ab);
    LOADH(0, Ah);

    for (int j = 0; j < WW; j += 2 * U) {
        LOADW(j + U, Bw0, Bw1, Bw2, Bb);   // j+U < WW always (j <= WW-2U)
        LOADH(j + U, Bh);
        COMPUTE8(j, Aw0, Aw1, Aw2, Ab, Ah);
        if (j + 2 * U < WW) {
            LOADW(j + 2 * U, Aw0, Aw1, Aw2, Ab);
            LOADH(j + 2 * U, Ah);
        }
        COMPUTE8(j + U, Bw0, Bw1, Bw2, Bb, Bh);
    }

    out[row] = a;
}

extern "C" void kernel_launch(void* const* d_in, const int* in_sizes, int n_in,
                              void* d_out, int out_size, void* d_ws, size_t ws_size,
                              hipStream_t stream) {
    const float* x = (const float*)d_in[0];
    const float* w = (const float*)d_in[1];
    const float* b = (const float*)d_in[2];
    float* out = (float*)d_out;
    unsigned long long* halo = (unsigned long long*)d_ws;
    neural_grid_scan<<<dim3(NB), dim3(64), 0, stream>>>(x, w, b, out, halo);
}